// Round 3
// baseline (92.034 us; speedup 1.0000x reference)
//
#include <hip/hip_runtime.h>

// CapsLayer2D, Gram-matrix MFMA version.
// dims: brc = B*R*C = 1024, I=128, DIN=16, K=32, DOUT=16.
// inputs: x [1024,128,16] f32; W [32,128,16,16] f32; out [1024,32,16] f32.
//
// Math: routing with b0 uniform collapses to
//   s0 = colsum(res)/128; G = res^T res (16x16, symmetric)
//   v0 = squash(s0); s1 = s0 + G v0; v1 = squash(s1); out = squash(s1 + G v1)
// so per task (brc,k) we only need s0 and G — both via MFMA from fp16 res.
//
// Pre-pass (unchanged from round 2, proven): bf16 hi/lo frag arrays in d_ws.
// Main: 512 thr / 8 waves; block = (16-brc tile) x (2 k sequential).
//   Phase A: per wave 16 i; K=32 packed as [hi|lo]: mfma(a,[Wh|Wl]) +
//   mfma(a, swap32([Wh|Wl])) = full (xh+xl)(Wh+Wl). res -> LDS fp16 in
//   G-fragment order (b128-readable).
//   Phase B: per task 4 b128 frag reads + 4 G-MFMAs + 4 ones-MFMAs (colsum),
//   then ~75-op epilogue using G symmetry (matvec = 4 bpermute + xor16/32).

using f32x4  = __attribute__((ext_vector_type(4))) float;
using bf16x8 = __attribute__((ext_vector_type(8))) short;
using f16x8  = __attribute__((ext_vector_type(8))) _Float16;
using i32x4  = __attribute__((ext_vector_type(4))) int;

constexpr size_t XFRAG_N = 64UL * 128 * 32 * 8;  // ushorts per x frag array (4 MB)
constexpr size_t WFRAG_N = 32UL * 128 * 32 * 8;  // ushorts per W frag array (2 MB)
constexpr size_t WS_NEEDED = (2 * XFRAG_N + 2 * WFRAG_N) * sizeof(ushort);  // 12 MB

constexpr int BRCS = 2056;   // res_lds halves per brc (2048 + 8 pad)

__device__ inline ushort f2bf(float f) {
    union { float f; uint u; } c{f};
    uint u = c.u;
    return (ushort)((u + 0x7fffu + ((u >> 16) & 1u)) >> 16);   // RNE
}
__device__ inline float bf2f(ushort b) {
    union { uint u; float f; } c{((uint)b) << 16};
    return c.f;
}

// ---------------- pre-pass: build bf16 hi/lo fragment arrays ----------------
__global__ __launch_bounds__(256)
void prepass(const float* __restrict__ x, const float* __restrict__ W,
             ushort* __restrict__ ws) {
    ushort* xh = ws;
    ushort* xl = xh + XFRAG_N;
    ushort* wh = xl + XFRAG_N;
    ushort* wl = wh + WFRAG_N;

    const int tid = blockIdx.x * 256 + threadIdx.x;
    float v[8];
    size_t dst;
    ushort* dh;
    ushort* dl;

    if (tid < 262144) {
        // x job: thread -> (brc, i, h); loads 8 contiguous floats (coalesced)
        const int h = tid & 1, i = (tid >> 1) & 127, brc = tid >> 8;
        const float* p = x + ((size_t)brc * 2048 + i * 16 + 8 * h);
        float4 v0 = *(const float4*)p, v1 = *(const float4*)(p + 4);
        v[0]=v0.x; v[1]=v0.y; v[2]=v0.z; v[3]=v0.w;
        v[4]=v1.x; v[5]=v1.y; v[6]=v1.z; v[7]=v1.w;
        const int tile = brc >> 4, r16 = brc & 15;
        const int l = 16 * h + r16;          // A-frag lane: row=l&15, d=8*(l>>4)+e
        dst = (((size_t)tile * 128 + i) * 32 + l) * 8;
        dh = xh; dl = xl;
    } else if (tid < 262144 + 131072) {
        // W job: thread -> (k, i, lane); B-frag lane: col o=l&15, d=8*(l>>4)+e
        const int t2 = tid - 262144;
        const int l = t2 & 31, i = (t2 >> 5) & 127, k = t2 >> 12;
        const int o = l & 15, dbase = 8 * (l >> 4);
#pragma unroll
        for (int e = 0; e < 8; ++e)
            v[e] = W[(((size_t)k * 128 + i) * 16 + dbase + e) * 16 + o];
        dst = (((size_t)k * 128 + i) * 32 + l) * 8;
        dh = wh; dl = wl;
    } else {
        return;
    }

    uint hp[4], lp[4];
#pragma unroll
    for (int j = 0; j < 4; ++j) {
        ushort h0 = f2bf(v[2*j]),     h1 = f2bf(v[2*j+1]);
        ushort l0 = f2bf(v[2*j]   - bf2f(h0));
        ushort l1 = f2bf(v[2*j+1] - bf2f(h1));
        hp[j] = (uint)h0 | ((uint)h1 << 16);
        lp[j] = (uint)l0 | ((uint)l1 << 16);
    }
    *(uint4*)(dh + dst) = make_uint4(hp[0], hp[1], hp[2], hp[3]);
    *(uint4*)(dl + dst) = make_uint4(lp[0], lp[1], lp[2], lp[3]);
}

// ---------------- main: MFMA res + Gram-matrix routing ----------------
__global__ __launch_bounds__(512, 4)
void caps_gram(const ushort* __restrict__ ws, float* __restrict__ out) {
    // res_lds layout (halves): brc*BRCS + (i>>3)*128 + o*8 + (i&7)
    // -> phase-B frag read per lane l: brc*BRCS + (4c + l>>4)*128 + (l&15)*8
    //    = contiguous 16B per lane, ascending with l (optimal b128 pattern).
    __shared__ _Float16 res_lds[16 * BRCS];   // 65,792 B -> 2 blocks/CU
    const ushort* xh = ws;
    const ushort* xl = xh + XFRAG_N;
    const ushort* wh = xl + XFRAG_N;
    const ushort* wl = wh + WFRAG_N;

    const int tid   = threadIdx.x;
    const int lane  = tid & 63;
    const int w     = tid >> 6;             // wave 0..7, owns i = 16w..16w+15
    const int kpair = blockIdx.x >> 6;      // 0..15
    const int tile  = blockIdx.x & 63;      // consecutive blocks share kpair

    const int q  = lane & 15;   // A-row (brc) / B,C-col (o)
    const int h  = lane >> 4;   // k-quadrant of frag / C row-group
    const int hl = h & 1;       // d-half within hi or lo copy

    // packed-K frag sources: lanes h<2 carry hi copy (k=d), h>=2 carry lo copy
    const ushort* xarr  = (h < 2) ? xh : xl;
    const ushort* warr  = (h < 2) ? wh : wl;
    const size_t  lslot = (size_t)(16 * hl + q) * 8;

    // preload this wave's 16 x-frags (reused for both k's)
    bf16x8 af[16];
    {
        const ushort* pa = xarr + (size_t)tile * 128 * 256 + lslot;
#pragma unroll
        for (int ii = 0; ii < 16; ++ii)
            af[ii] = *(const bf16x8*)(pa + (size_t)(w * 16 + ii) * 256);
    }

    f16x8 ones;
#pragma unroll
    for (int e = 0; e < 8; ++e) ones[e] = (_Float16)1.0f;

    for (int kk = 0; kk < 2; ++kk) {
        const int k = kpair * 2 + kk;
        if (kk) __syncthreads();            // res_lds readers of prev k done

        // ---- phase A: res[i][brc][o] -> LDS fp16 (G-frag order) ----
        {
            const ushort* pb = warr + (size_t)k * 128 * 256 + lslot;
#pragma unroll 4
            for (int ii = 0; ii < 16; ++ii) {
                const int i = w * 16 + ii;
                i32x4 bi = *(const i32x4*)(pb + (size_t)i * 256);
                i32x4 bs;
                bs[0] = __shfl_xor(bi[0], 32); bs[1] = __shfl_xor(bi[1], 32);
                bs[2] = __shfl_xor(bi[2], 32); bs[3] = __shfl_xor(bi[3], 32);
                f32x4 acc = {0.f, 0.f, 0.f, 0.f};
                // [xh|xl]·[Wh|Wl] = hh + ll ; [xh|xl]·[Wl|Wh] = hl + lh
                acc = __builtin_amdgcn_mfma_f32_16x16x32_bf16(
                          af[ii], __builtin_bit_cast(bf16x8, bi), acc, 0, 0, 0);
                acc = __builtin_amdgcn_mfma_f32_16x16x32_bf16(
                          af[ii], __builtin_bit_cast(bf16x8, bs), acc, 0, 0, 0);
                // C layout: col=o=lane&15, row=brc=4*(lane>>4)+r
                const int wb = (i >> 3) * 128 + q * 8 + (i & 7);
#pragma unroll
                for (int r = 0; r < 4; ++r)
                    res_lds[(4 * h + r) * BRCS + wb] = (_Float16)acc[r];
            }
        }
        __syncthreads();

        // ---- phase B: per task (brc,k): G = res^T res, s0 = colsum/128 ----
#pragma unroll
        for (int t = 0; t < 2; ++t) {
            const int brc = 2 * w + t;
            f32x4 g4 = {0.f, 0.f, 0.f, 0.f};   // G[4h+p][q]
            f32x4 s4 = {0.f, 0.f, 0.f, 0.f};   // colsum[q] (rows identical)
            const _Float16* rp = &res_lds[brc * BRCS + h * 128 + q * 8];
#pragma unroll
            for (int c = 0; c < 4; ++c) {
                f16x8 f = *(const f16x8*)(rp + c * 512);
                g4 = __builtin_amdgcn_mfma_f32_16x16x32_f16(f, f, g4, 0, 0, 0);
                s4 = __builtin_amdgcn_mfma_f32_16x16x32_f16(ones, f, s4, 0, 0, 0);
            }

            // epilogue (all fp32, per lane value indexed by col o=q)
            float s0 = s4[0] * 0.0078125f;
            float x2 = s0 * s0;
            x2 += __shfl_xor(x2, 1); x2 += __shfl_xor(x2, 2);
            x2 += __shfl_xor(x2, 4); x2 += __shfl_xor(x2, 8);
            float sc = (x2 / (1.f + x2)) / sqrtf(x2 + 1e-7f);
            float v = s0 * sc;
            // u = G v (G symmetric): lane sums its 4 rows, reduce over h
            float vq0 = __shfl(v, 4 * h + 0), vq1 = __shfl(v, 4 * h + 1);
            float vq2 = __shfl(v, 4 * h + 2), vq3 = __shfl(v, 4 * h + 3);
            float pp = fmaf(g4[0], vq0, fmaf(g4[1], vq1,
                       fmaf(g4[2], vq2, g4[3] * vq3)));
            pp += __shfl_xor(pp, 16); pp += __shfl_xor(pp, 32);
            float s1 = s0 + pp;

            x2 = s1 * s1;
            x2 += __shfl_xor(x2, 1); x2 += __shfl_xor(x2, 2);
            x2 += __shfl_xor(x2, 4); x2 += __shfl_xor(x2, 8);
            sc = (x2 / (1.f + x2)) / sqrtf(x2 + 1e-7f);
            v = s1 * sc;
            vq0 = __shfl(v, 4 * h + 0); vq1 = __shfl(v, 4 * h + 1);
            vq2 = __shfl(v, 4 * h + 2); vq3 = __shfl(v, 4 * h + 3);
            pp = fmaf(g4[0], vq0, fmaf(g4[1], vq1,
                 fmaf(g4[2], vq2, g4[3] * vq3)));
            pp += __shfl_xor(pp, 16); pp += __shfl_xor(pp, 32);
            float s2 = s1 + pp;

            x2 = s2 * s2;
            x2 += __shfl_xor(x2, 1); x2 += __shfl_xor(x2, 2);
            x2 += __shfl_xor(x2, 4); x2 += __shfl_xor(x2, 8);
            sc = (x2 / (1.f + x2)) / sqrtf(x2 + 1e-7f);

            if (h == 0)
                out[(((size_t)(tile * 16 + brc)) * 32 + k) * 16 + q] = s2 * sc;
        }
    }
}

// ---------------- fallback (round-1 fp32 kernel) if ws too small ----------------
constexpr int WSTRIDE = 260;

__global__ __launch_bounds__(256)
void caps_fused(const float* __restrict__ x,
                const float* __restrict__ W,
                float* __restrict__ out)
{
    __shared__ float wlds[32 * WSTRIDE];

    const int tid  = threadIdx.x;
    const int lane = tid & 63;
    const int wave = tid >> 6;

    const int b    = blockIdx.x;
    const int tq   = b & 15;
    const int kq   = (b >> 4) & 7;
    const int sg   = b >> 7;
    const int k    = (sg & 3) * 8 + kq;
    const int tile = (sg >> 2) * 16 + tq;

    const int brc0 = tile * 8 + wave * 2;
    const int il = lane & 31;
    const int oh = lane >> 5;
    const int ob = oh * 8;

    float res[2][4][8];
#pragma unroll
    for (int t = 0; t < 2; ++t)
#pragma unroll
        for (int r = 0; r < 4; ++r)
#pragma unroll
            for (int q = 0; q < 8; ++q) res[t][r][q] = 0.0f;

    const float* Wk = W + (size_t)k * (128 * 16 * 16);

#pragma unroll
    for (int c = 0; c < 4; ++c) {
        __syncthreads();
#pragma unroll
        for (int j = 0; j < 8; ++j) {
            const int e    = j * 1024 + tid * 4;
            const int irow = e >> 8;
            const int rem  = e & 255;
            *reinterpret_cast<float4*>(&wlds[irow * WSTRIDE + rem]) =
                *reinterpret_cast<const float4*>(&Wk[c * 8192 + e]);
        }
        __syncthreads();

        const int i = c * 32 + il;
        float xv[2][16];
#pragma unroll
        for (int t = 0; t < 2; ++t) {
            const float* xp = x + ((size_t)(brc0 + t) * 128 + i) * 16;
#pragma unroll
            for (int q4 = 0; q4 < 4; ++q4) {
                float4 v4 = *reinterpret_cast<const float4*>(&xp[q4 * 4]);
                xv[t][q4*4+0] = v4.x; xv[t][q4*4+1] = v4.y;
                xv[t][q4*4+2] = v4.z; xv[t][q4*4+3] = v4.w;
            }
        }
        const float* wrow = &wlds[il * WSTRIDE + ob];
#pragma unroll
        for (int d = 0; d < 16; ++d) {
            float4 wa = *reinterpret_cast<const float4*>(&wrow[d * 16]);
            float4 wb = *reinterpret_cast<const float4*>(&wrow[d * 16 + 4]);
            const float w8[8] = {wa.x, wa.y, wa.z, wa.w, wb.x, wb.y, wb.z, wb.w};
#pragma unroll
            for (int t = 0; t < 2; ++t)
#pragma unroll
                for (int q = 0; q < 8; ++q)
                    res[t][c][q] = fmaf(xv[t][d], w8[q], res[t][c][q]);
        }
    }

#pragma unroll
    for (int t = 0; t < 2; ++t) {
        float bb[4] = {1.0f/128.0f, 1.0f/128.0f, 1.0f/128.0f, 1.0f/128.0f};
        float v[8];
#pragma unroll
        for (int iter = 0; iter < 3; ++iter) {
            float s[8];
#pragma unroll
            for (int q = 0; q < 8; ++q) {
                s[q] = bb[0] * res[t][0][q];
#pragma unroll
                for (int r = 1; r < 4; ++r) s[q] = fmaf(bb[r], res[t][r][q], s[q]);
            }
#pragma unroll
            for (int m = 1; m <= 16; m <<= 1)
#pragma unroll
                for (int q = 0; q < 8; ++q) s[q] += __shfl_xor(s[q], m);
            float loc = 0.0f;
#pragma unroll
            for (int q = 0; q < 8; ++q) loc = fmaf(s[q], s[q], loc);
            const float sq = loc + __shfl_xor(loc, 32);
            const float scale = (sq / (1.0f + sq)) / sqrtf(sq + 1e-7f);
#pragma unroll
            for (int q = 0; q < 8; ++q) v[q] = s[q] * scale;
            if (iter < 2) {
#pragma unroll
                for (int r = 0; r < 4; ++r) {
                    float tp = 0.0f;
#pragma unroll
                    for (int q = 0; q < 8; ++q) tp = fmaf(res[t][r][q], v[q], tp);
                    bb[r] += tp + __shfl_xor(tp, 32);
                }
            }
        }
        if (il == 0) {
            float* op = out + ((size_t)(brc0 + t) * 32 + k) * 16 + ob;
            *reinterpret_cast<float4*>(&op[0]) = make_float4(v[0], v[1], v[2], v[3]);
            *reinterpret_cast<float4*>(&op[4]) = make_float4(v[4], v[5], v[6], v[7]);
        }
    }
}

extern "C" void kernel_launch(void* const* d_in, const int* in_sizes, int n_in,
                              void* d_out, int out_size, void* d_ws, size_t ws_size,
                              hipStream_t stream) {
    const float* x  = (const float*)d_in[0];
    const float* W  = (const float*)d_in[1];
    float* out      = (float*)d_out;
    if (ws_size >= WS_NEEDED && d_ws != nullptr) {
        ushort* ws = (ushort*)d_ws;
        hipLaunchKernelGGL(prepass,   dim3(1536), dim3(256), 0, stream, x, W, ws);
        hipLaunchKernelGGL(caps_gram, dim3(1024), dim3(512), 0, stream, ws, out);
    } else {
        hipLaunchKernelGGL(caps_fused, dim3(4096), dim3(256), 0, stream, x, W, out);
    }
}

// Round 5
// 37.092 us; speedup vs baseline: 2.4812x; 2.4812x over previous
//
#include <hip/hip_runtime.h>

// CapsLayer2D, Gram-matrix MFMA version, f16 hi/lo single-MFMA predictions.
// dims: brc = B*R*C = 1024, I=128, DIN=16, K=32, DOUT=16.
// inputs: x [1024,128,16] f32; W [32,128,16,16] f32; out [1024,32,16] f32.
//
// Math (verified round 3): routing with uniform b0 collapses to
//   s0 = colsum(res)/128; G = res^T res (16x16, symmetric)
//   v0 = squash(s0); s1 = s0 + G v0; v1 = squash(s1); out = squash(s1 + G v1)
//
// Prediction trick: x = xh + xl (f16 hi/lo, near-exact). A-frag = [xh|xl]
// (K slots 0-15 = xh, 16-31 = xl); B-frag = [W|W] (same W f16 in both K
// halves, lanes 32-63 read the SAME addresses as 0-31 -> coalesced dedup).
// One mfma_f32_16x16x32_f16 = (xh+xl)·W = x·W. No lane swaps, no bf16 splits.
//
// Main: 512 thr / 8 waves; block = (16-brc tile) x (4 k sequential).
// Phase A: wave owns 16 i; 1 MFMA/i; acc packed along i (groups of 4) ->
// ds_write_b64 into res_lds [brc][i>>3][o][i&7] (b128-readable by phase B).
// Phase B: per task 4 b128 reads + 8 MFMAs (G + colsum), epilogue with DPP
// row-16 reductions (VALU pipe, not LDS).

using f32x4 = __attribute__((ext_vector_type(4))) float;
using h16x8 = __attribute__((ext_vector_type(8))) _Float16;
using h16x4 = __attribute__((ext_vector_type(4))) _Float16;

constexpr int BRCS = 2056;   // res_lds halves per brc (2048 + 8 pad)

constexpr size_t XFRAG_N = 64UL * 128 * 64 * 8;  // halves: x frags (8 MB)
constexpr size_t WFRAG_N = 32UL * 128 * 32 * 8;  // halves: W frags (2 MB)
constexpr size_t WS_NEEDED = (XFRAG_N + WFRAG_N) * 2;  // 10 MB

// ---------------- pre-pass: build f16 fragment arrays ----------------
__global__ __launch_bounds__(256)
void prepass(const float* __restrict__ x, const float* __restrict__ W,
             _Float16* __restrict__ ws) {
    _Float16* xf = ws;
    _Float16* wf = ws + XFRAG_N;

    const int tid = blockIdx.x * 256 + threadIdx.x;

    if (tid < 262144) {
        // x job: thread -> (brc, i, h); reads 8 contiguous floats.
        const int h = tid & 1, i = (tid >> 1) & 127, brc = tid >> 8;
        const float* p = x + ((size_t)brc * 2048 + i * 16 + 8 * h);
        float4 v0 = *(const float4*)p, v1 = *(const float4*)(p + 4);
        float v[8] = {v0.x, v0.y, v0.z, v0.w, v1.x, v1.y, v1.z, v1.w};
        h16x8 hi, lo;
#pragma unroll
        for (int e = 0; e < 8; ++e) {
            hi[e] = (_Float16)v[e];
            lo[e] = (_Float16)(v[e] - (float)hi[e]);
        }
        const int tile = brc >> 4, r16 = brc & 15;
        // A-frag slot l (0..63): row = l&15 (brc in tile), k = 8*(l>>4)+e.
        // K 0-15 = xh (slots j=0,1), K 16-31 = xl (slots j=2,3).
        _Float16* base = xf + ((size_t)(tile * 128 + i)) * 512;
        *(h16x8*)(base + (size_t)(16 * h + r16) * 8)       = hi;
        *(h16x8*)(base + (size_t)(16 * (h + 2) + r16) * 8) = lo;
    } else if (tid < 262144 + 131072) {
        // W job: thread -> (k, i, s); 32 slots/i: col o = s&15, d = 8*(s>>4)+e.
        const int t2 = tid - 262144;
        const int s = t2 & 31, i = (t2 >> 5) & 127, k = t2 >> 12;
        const int o = s & 15, dbase = 8 * (s >> 4);
        h16x8 wv;
#pragma unroll
        for (int e = 0; e < 8; ++e)
            wv[e] = (_Float16)W[(((size_t)k * 128 + i) * 16 + dbase + e) * 16 + o];
        *(h16x8*)(wf + ((size_t)(k * 128 + i) * 32 + s) * 8) = wv;
    }
}

// DPP helpers: sum over each 16-lane row (all lanes end with the row sum).
// dpp_ctrl must be a compile-time constant -> template parameter.
template <int CTRL>
__device__ inline float dpp_add(float x) {
    int v = __builtin_amdgcn_update_dpp(
        0, __builtin_bit_cast(int, x), CTRL, 0xf, 0xf, true);
    return x + __builtin_bit_cast(float, v);
}
__device__ inline float row16_sum(float x) {
    x = dpp_add<0xB1>(x);    // quad_perm(1,0,3,2)  : xor 1
    x = dpp_add<0x4E>(x);    // quad_perm(2,3,0,1)  : xor 2
    x = dpp_add<0x141>(x);   // row_half_mirror     : xor 7 within 8
    x = dpp_add<0x140>(x);   // row_mirror          : xor 15 within 16
    return x;
}

// ---------------- main: MFMA res + Gram routing ----------------
__global__ __launch_bounds__(512, 4)
void caps_g4(const _Float16* __restrict__ ws, float* __restrict__ out) {
    __shared__ _Float16 res_lds[16 * BRCS];   // 65,792 B -> 2 blocks/CU
    const _Float16* xf = ws;
    const _Float16* wf = ws + XFRAG_N;

    const int tid  = threadIdx.x;
    const int lane = tid & 63;
    const int w    = tid >> 6;            // wave 0..7, owns i = 16w..16w+15
    const int kq   = blockIdx.x >> 6;     // 0..7 (4 k's each)
    const int tile = blockIdx.x & 63;     // consecutive blocks share kq

    const int q  = lane & 15;             // col (o) / A-row (brc)
    const int hq = lane >> 4;             // 0..3
    const int hl = hq & 1;

    // preload this wave's 16 x A-frags ([xh|xl]), reused for all 4 k's
    h16x8 af[16];
    {
        const _Float16* xb = xf + (size_t)(tile * 128 + w * 16) * 512 + lane * 8;
#pragma unroll
        for (int ii = 0; ii < 16; ++ii)
            af[ii] = *(const h16x8*)(xb + (size_t)ii * 512);
    }

    h16x8 ones;
#pragma unroll
    for (int e = 0; e < 8; ++e) ones[e] = (_Float16)1.0f;

    for (int kk = 0; kk < 4; ++kk) {
        const int k = kq * 4 + kk;
        if (kk) __syncthreads();          // prev k's res_lds readers done

        // ---- phase A: res[i][brc][o] -> LDS f16 ----
        {
            // B-frag: slot (16*hl + q); lanes 32-63 read same addr as 0-31.
            const _Float16* wb = wf + (size_t)k * 32768 + (size_t)(16 * hl + q) * 8
                                    + (size_t)(w * 16) * 256;
#pragma unroll
            for (int g = 0; g < 4; ++g) {       // groups of 4 i
                f32x4 ac[4];
#pragma unroll
                for (int m = 0; m < 4; ++m) {
                    const int ii = g * 4 + m;
                    h16x8 b = *(const h16x8*)(wb + (size_t)ii * 256);
                    f32x4 z = {0.f, 0.f, 0.f, 0.f};
                    ac[m] = __builtin_amdgcn_mfma_f32_16x16x32_f16(af[ii], b, z,
                                                                   0, 0, 0);
                }
                const int i0  = w * 16 + g * 4;
                const int col = (i0 >> 3) * 128 + q * 8 + (i0 & 7); // i0&7 in {0,4}
#pragma unroll
                for (int r = 0; r < 4; ++r) {
                    // C layout: col = lane&15 (o), row = 4*(lane>>4)+r (brc)
                    h16x4 hv = {(_Float16)ac[0][r], (_Float16)ac[1][r],
                                (_Float16)ac[2][r], (_Float16)ac[3][r]};
                    *(h16x4*)&res_lds[(4 * hq + r) * BRCS + col] = hv;
                }
            }
        }
        __syncthreads();

        // ---- phase B: per task (brc,k): G = res^T res, s0 = colsum/128 ----
#pragma unroll
        for (int t = 0; t < 2; ++t) {
            const int brc = 2 * w + t;
            f32x4 g4 = {0.f, 0.f, 0.f, 0.f};   // G[4hq+p][q]
            f32x4 s4 = {0.f, 0.f, 0.f, 0.f};   // colsum[q]
            const _Float16* rp = &res_lds[brc * BRCS + hq * 128 + q * 8];
#pragma unroll
            for (int c = 0; c < 4; ++c) {
                h16x8 f = *(const h16x8*)(rp + c * 512);
                g4 = __builtin_amdgcn_mfma_f32_16x16x32_f16(f, f, g4, 0, 0, 0);
                s4 = __builtin_amdgcn_mfma_f32_16x16x32_f16(ones, f, s4, 0, 0, 0);
            }

            // epilogue (fp32; per-lane value indexed by col o = q)
            float s0 = s4[0] * 0.0078125f;
            float x2 = row16_sum(s0 * s0);
            float sc = (x2 / (1.f + x2)) / sqrtf(x2 + 1e-7f);
            float v  = s0 * sc;

            // u = G v (G symmetric): lane sums its 4 rows, reduce over hq
            float vq0 = __shfl(v, 4 * hq + 0), vq1 = __shfl(v, 4 * hq + 1);
            float vq2 = __shfl(v, 4 * hq + 2), vq3 = __shfl(v, 4 * hq + 3);
            float pp = fmaf(g4[0], vq0, fmaf(g4[1], vq1,
                       fmaf(g4[2], vq2, g4[3] * vq3)));
            pp += __shfl_xor(pp, 16); pp += __shfl_xor(pp, 32);
            float s1 = s0 + pp;

            x2 = row16_sum(s1 * s1);
            sc = (x2 / (1.f + x2)) / sqrtf(x2 + 1e-7f);
            v  = s1 * sc;
            vq0 = __shfl(v, 4 * hq + 0); vq1 = __shfl(v, 4 * hq + 1);
            vq2 = __shfl(v, 4 * hq + 2); vq3 = __shfl(v, 4 * hq + 3);
            pp = fmaf(g4[0], vq0, fmaf(g4[1], vq1,
                 fmaf(g4[2], vq2, g4[3] * vq3)));
            pp += __shfl_xor(pp, 16); pp += __shfl_xor(pp, 32);
            float s2 = s1 + pp;

            x2 = row16_sum(s2 * s2);
            sc = (x2 / (1.f + x2)) / sqrtf(x2 + 1e-7f);

            if (hq == 0)
                out[(((size_t)(tile * 16 + brc)) * 32 + k) * 16 + q] = s2 * sc;
        }
    }
}

// ---------------- fallback (round-1 fp32 kernel) if ws too small ----------------
constexpr int WSTRIDE = 260;

__global__ __launch_bounds__(256)
void caps_fused(const float* __restrict__ x,
                const float* __restrict__ W,
                float* __restrict__ out)
{
    __shared__ float wlds[32 * WSTRIDE];

    const int tid  = threadIdx.x;
    const int lane = tid & 63;
    const int wave = tid >> 6;

    const int b    = blockIdx.x;
    const int tq   = b & 15;
    const int kq   = (b >> 4) & 7;
    const int sg   = b >> 7;
    const int k    = (sg & 3) * 8 + kq;
    const int tile = (sg >> 2) * 16 + tq;

    const int brc0 = tile * 8 + wave * 2;
    const int il = lane & 31;
    const int oh = lane >> 5;
    const int ob = oh * 8;

    float res[2][4][8];
#pragma unroll
    for (int t = 0; t < 2; ++t)
#pragma unroll
        for (int r = 0; r < 4; ++r)
#pragma unroll
            for (int q = 0; q < 8; ++q) res[t][r][q] = 0.0f;

    const float* Wk = W + (size_t)k * (128 * 16 * 16);

#pragma unroll
    for (int c = 0; c < 4; ++c) {
        __syncthreads();
#pragma unroll
        for (int j = 0; j < 8; ++j) {
            const int e    = j * 1024 + tid * 4;
            const int irow = e >> 8;
            const int rem  = e & 255;
            *reinterpret_cast<float4*>(&wlds[irow * WSTRIDE + rem]) =
                *reinterpret_cast<const float4*>(&Wk[c * 8192 + e]);
        }
        __syncthreads();

        const int i = c * 32 + il;
        float xv[2][16];
#pragma unroll
        for (int t = 0; t < 2; ++t) {
            const float* xp = x + ((size_t)(brc0 + t) * 128 + i) * 16;
#pragma unroll
            for (int q4 = 0; q4 < 4; ++q4) {
                float4 v4 = *reinterpret_cast<const float4*>(&xp[q4 * 4]);
                xv[t][q4*4+0] = v4.x; xv[t][q4*4+1] = v4.y;
                xv[t][q4*4+2] = v4.z; xv[t][q4*4+3] = v4.w;
            }
        }
        const float* wrow = &wlds[il * WSTRIDE + ob];
#pragma unroll
        for (int d = 0; d < 16; ++d) {
            float4 wa = *reinterpret_cast<const float4*>(&wrow[d * 16]);
            float4 wb = *reinterpret_cast<const float4*>(&wrow[d * 16 + 4]);
            const float w8[8] = {wa.x, wa.y, wa.z, wa.w, wb.x, wb.y, wb.z, wb.w};
#pragma unroll
            for (int t = 0; t < 2; ++t)
#pragma unroll
                for (int q = 0; q < 8; ++q)
                    res[t][c][q] = fmaf(xv[t][d], w8[q], res[t][c][q]);
        }
    }

#pragma unroll
    for (int t = 0; t < 2; ++t) {
        float bb[4] = {1.0f/128.0f, 1.0f/128.0f, 1.0f/128.0f, 1.0f/128.0f};
        float v[8];
#pragma unroll
        for (int iter = 0; iter < 3; ++iter) {
            float s[8];
#pragma unroll
            for (int q = 0; q < 8; ++q) {
                s[q] = bb[0] * res[t][0][q];
#pragma unroll
                for (int r = 1; r < 4; ++r) s[q] = fmaf(bb[r], res[t][r][q], s[q]);
            }
#pragma unroll
            for (int m = 1; m <= 16; m <<= 1)
#pragma unroll
                for (int q = 0; q < 8; ++q) s[q] += __shfl_xor(s[q], m);
            float loc = 0.0f;
#pragma unroll
            for (int q = 0; q < 8; ++q) loc = fmaf(s[q], s[q], loc);
            const float sq = loc + __shfl_xor(loc, 32);
            const float scale = (sq / (1.0f + sq)) / sqrtf(sq + 1e-7f);
#pragma unroll
            for (int q = 0; q < 8; ++q) v[q] = s[q] * scale;
            if (iter < 2) {
#pragma unroll
                for (int r = 0; r < 4; ++r) {
                    float tp = 0.0f;
#pragma unroll
                    for (int q = 0; q < 8; ++q) tp = fmaf(res[t][r][q], v[q], tp);
                    bb[r] += tp + __shfl_xor(tp, 32);
                }
            }
        }
        if (il == 0) {
            float* op = out + ((size_t)(brc0 + t) * 32 + k) * 16 + ob;
            *reinterpret_cast<float4*>(&op[0]) = make_float4(v[0], v[1], v[2], v[3]);
            *reinterpret_cast<float4*>(&op[4]) = make_float4(v[4], v[5], v[6], v[7]);
        }
    }
}

extern "C" void kernel_launch(void* const* d_in, const int* in_sizes, int n_in,
                              void* d_out, int out_size, void* d_ws, size_t ws_size,
                              hipStream_t stream) {
    const float* x  = (const float*)d_in[0];
    const float* W  = (const float*)d_in[1];
    float* out      = (float*)d_out;
    if (ws_size >= WS_NEEDED && d_ws != nullptr) {
        _Float16* ws = (_Float16*)d_ws;
        hipLaunchKernelGGL(prepass, dim3(1536), dim3(256), 0, stream, x, W, ws);
        hipLaunchKernelGGL(caps_g4, dim3(512),  dim3(512), 0, stream, ws, out);
    } else {
        hipLaunchKernelGGL(caps_fused, dim3(4096), dim3(256), 0, stream, x, W, out);
    }
}

// Round 6
// 34.198 us; speedup vs baseline: 2.6912x; 1.0846x over previous
//
#include <hip/hip_runtime.h>

// CapsLayer2D, Gram-matrix MFMA version, f16 hi/lo single-MFMA predictions.
// dims: brc = B*R*C = 1024, I=128, DIN=16, K=32, DOUT=16.
// inputs: x [1024,128,16] f32; W [32,128,16,16] f32; out [1024,32,16] f32.
//
// Math (verified round 3/5): routing with uniform b0 collapses to
//   s0 = colsum(res)/128; G = res^T res (16x16, symmetric)
//   v0 = squash(s0); s1 = s0 + G v0; v1 = squash(s1); out = squash(s1 + G v1)
//
// Prediction trick (verified round 5): x = xh + xl (f16 hi/lo). A-frag =
// [xh|xl] (K 0-15 = xh, 16-31 = xl); B-frag = [W|W] (lanes 32-63 read the
// SAME addresses as 0-31 -> coalesced dedup). One mfma_f32_16x16x32_f16
// = (xh+xl)·W = x·W.
//
// Round-6 deltas (instruction-count attack):
//  - squash scale via raw v_rcp_f32 / v_rsq_f32 (approx ok: threshold 1.8e-2)
//  - phase A writes: 8 x ds_write_b128 (8-i super-groups) instead of 16 b64
//  - res_lds strides (544/136/BRCS=2184): phase-B ds_read_b128 banks
//    4*(hq+q) -> ~2-way (free), was 4-way.

using f32x4 = __attribute__((ext_vector_type(4))) float;
using h16x8 = __attribute__((ext_vector_type(8))) _Float16;

// res_lds element (i,o) at offset (i>>5)*544 + ((i>>3)&3)*136 + o*8 + (i&7)
constexpr int BRCS = 2184;   // halves per brc row (4*544 + pad)

constexpr size_t XFRAG_N = 64UL * 128 * 64 * 8;  // halves: x frags (8 MB)
constexpr size_t WFRAG_N = 32UL * 128 * 32 * 8;  // halves: W frags (2 MB)
constexpr size_t WS_NEEDED = (XFRAG_N + WFRAG_N) * 2;  // 10 MB

// ---------------- pre-pass: build f16 fragment arrays ----------------
__global__ __launch_bounds__(256)
void prepass(const float* __restrict__ x, const float* __restrict__ W,
             _Float16* __restrict__ ws) {
    _Float16* xf = ws;
    _Float16* wf = ws + XFRAG_N;

    const int tid = blockIdx.x * 256 + threadIdx.x;

    if (tid < 262144) {
        // x job: thread -> (brc, i, h); reads 8 contiguous floats.
        const int h = tid & 1, i = (tid >> 1) & 127, brc = tid >> 8;
        const float* p = x + ((size_t)brc * 2048 + i * 16 + 8 * h);
        float4 v0 = *(const float4*)p, v1 = *(const float4*)(p + 4);
        float v[8] = {v0.x, v0.y, v0.z, v0.w, v1.x, v1.y, v1.z, v1.w};
        h16x8 hi, lo;
#pragma unroll
        for (int e = 0; e < 8; ++e) {
            hi[e] = (_Float16)v[e];
            lo[e] = (_Float16)(v[e] - (float)hi[e]);
        }
        const int tile = brc >> 4, r16 = brc & 15;
        // A-frag slot l (0..63): row = l&15 (brc in tile), k = 8*(l>>4)+e.
        // K 0-15 = xh (slots j=0,1), K 16-31 = xl (slots j=2,3).
        _Float16* base = xf + ((size_t)(tile * 128 + i)) * 512;
        *(h16x8*)(base + (size_t)(16 * h + r16) * 8)       = hi;
        *(h16x8*)(base + (size_t)(16 * (h + 2) + r16) * 8) = lo;
    } else if (tid < 262144 + 131072) {
        // W job: thread -> (k, i, s); 32 slots/i: col o = s&15, d = 8*(s>>4)+e.
        const int t2 = tid - 262144;
        const int s = t2 & 31, i = (t2 >> 5) & 127, k = t2 >> 12;
        const int o = s & 15, dbase = 8 * (s >> 4);
        h16x8 wv;
#pragma unroll
        for (int e = 0; e < 8; ++e)
            wv[e] = (_Float16)W[(((size_t)k * 128 + i) * 16 + dbase + e) * 16 + o];
        *(h16x8*)(wf + ((size_t)(k * 128 + i) * 32 + s) * 8) = wv;
    }
}

// DPP helpers: sum over each 16-lane row (all lanes end with the row sum).
template <int CTRL>
__device__ inline float dpp_add(float x) {
    int v = __builtin_amdgcn_update_dpp(
        0, __builtin_bit_cast(int, x), CTRL, 0xf, 0xf, true);
    return x + __builtin_bit_cast(float, v);
}
__device__ inline float row16_sum(float x) {
    x = dpp_add<0xB1>(x);    // quad_perm(1,0,3,2)  : xor 1
    x = dpp_add<0x4E>(x);    // quad_perm(2,3,0,1)  : xor 2
    x = dpp_add<0x141>(x);   // row_half_mirror     : xor 7 within 8
    x = dpp_add<0x140>(x);   // row_mirror          : xor 15 within 16
    return x;
}

// squash scale from |s|^2: (n/(1+n)) / sqrt(n+eps), via raw rcp/rsq.
__device__ inline float squash_scale(float n) {
    float rcp, rsq;
    asm("v_rcp_f32 %0, %1" : "=v"(rcp) : "v"(1.0f + n));
    asm("v_rsq_f32 %0, %1" : "=v"(rsq) : "v"(n + 1e-7f));
    return n * rcp * rsq;
}

// ---------------- main: MFMA res + Gram routing ----------------
__global__ __launch_bounds__(512, 4)
void caps_g4(const _Float16* __restrict__ ws, float* __restrict__ out) {
    __shared__ _Float16 res_lds[16 * BRCS];   // 69,888 B -> 2 blocks/CU
    const _Float16* xf = ws;
    const _Float16* wf = ws + XFRAG_N;

    const int tid  = threadIdx.x;
    const int lane = tid & 63;
    const int w    = tid >> 6;            // wave 0..7, owns i = 16w..16w+15
    const int kq   = blockIdx.x >> 6;     // 0..7 (4 k's each)
    const int tile = blockIdx.x & 63;     // consecutive blocks share kq

    const int q  = lane & 15;             // col (o) / A-row (brc)
    const int hq = lane >> 4;             // 0..3
    const int hl = hq & 1;

    // preload this wave's 16 x A-frags ([xh|xl]), reused for all 4 k's
    h16x8 af[16];
    {
        const _Float16* xb = xf + (size_t)(tile * 128 + w * 16) * 512 + lane * 8;
#pragma unroll
        for (int ii = 0; ii < 16; ++ii)
            af[ii] = *(const h16x8*)(xb + (size_t)ii * 512);
    }

    h16x8 ones;
#pragma unroll
    for (int e = 0; e < 8; ++e) ones[e] = (_Float16)1.0f;

    for (int kk = 0; kk < 4; ++kk) {
        const int k = kq * 4 + kk;
        if (kk) __syncthreads();          // prev k's res_lds readers done

        // ---- phase A: res[i][brc][o] -> LDS f16 ----
        {
            // B-frag: slot (16*hl + q); lanes 32-63 read same addr as 0-31.
            const _Float16* wb = wf + (size_t)k * 32768 + (size_t)(16 * hl + q) * 8
                                    + (size_t)(w * 16) * 256;
#pragma unroll
            for (int s = 0; s < 2; ++s) {      // super-groups of 8 i
                f32x4 ac[8];
#pragma unroll
                for (int m = 0; m < 8; ++m) {
                    const int ii = s * 8 + m;
                    h16x8 b = *(const h16x8*)(wb + (size_t)ii * 256);
                    f32x4 z = {0.f, 0.f, 0.f, 0.f};
                    ac[m] = __builtin_amdgcn_mfma_f32_16x16x32_f16(af[ii], b, z,
                                                                   0, 0, 0);
                }
                const int i0   = w * 16 + s * 8;            // multiple of 8
                const int cb   = (i0 >> 5) * 544 + ((i0 >> 3) & 3) * 136 + q * 8;
#pragma unroll
                for (int r = 0; r < 4; ++r) {
                    // C layout: col = lane&15 (o), row = 4*(lane>>4)+r (brc)
                    h16x8 hv = {(_Float16)ac[0][r], (_Float16)ac[1][r],
                                (_Float16)ac[2][r], (_Float16)ac[3][r],
                                (_Float16)ac[4][r], (_Float16)ac[5][r],
                                (_Float16)ac[6][r], (_Float16)ac[7][r]};
                    *(h16x8*)&res_lds[(4 * hq + r) * BRCS + cb] = hv;
                }
            }
        }
        __syncthreads();

        // ---- phase B: per task (brc,k): G = res^T res, s0 = colsum/128 ----
#pragma unroll
        for (int t = 0; t < 2; ++t) {
            const int brc = 2 * w + t;
            f32x4 g4 = {0.f, 0.f, 0.f, 0.f};   // G[4hq+p][q]
            f32x4 s4 = {0.f, 0.f, 0.f, 0.f};   // colsum[q]
            const _Float16* rp = &res_lds[brc * BRCS + hq * 136 + q * 8];
#pragma unroll
            for (int c = 0; c < 4; ++c) {
                h16x8 f = *(const h16x8*)(rp + c * 544);
                g4 = __builtin_amdgcn_mfma_f32_16x16x32_f16(f, f, g4, 0, 0, 0);
                s4 = __builtin_amdgcn_mfma_f32_16x16x32_f16(ones, f, s4, 0, 0, 0);
            }

            // epilogue (fp32; per-lane value indexed by col o = q)
            float s0 = s4[0] * 0.0078125f;
            float sc = squash_scale(row16_sum(s0 * s0));
            float v  = s0 * sc;

            // u = G v (G symmetric): lane sums its 4 rows, reduce over hq
            float vq0 = __shfl(v, 4 * hq + 0), vq1 = __shfl(v, 4 * hq + 1);
            float vq2 = __shfl(v, 4 * hq + 2), vq3 = __shfl(v, 4 * hq + 3);
            float pp = fmaf(g4[0], vq0, fmaf(g4[1], vq1,
                       fmaf(g4[2], vq2, g4[3] * vq3)));
            pp += __shfl_xor(pp, 16); pp += __shfl_xor(pp, 32);
            float s1 = s0 + pp;

            sc = squash_scale(row16_sum(s1 * s1));
            v  = s1 * sc;
            vq0 = __shfl(v, 4 * hq + 0); vq1 = __shfl(v, 4 * hq + 1);
            vq2 = __shfl(v, 4 * hq + 2); vq3 = __shfl(v, 4 * hq + 3);
            pp = fmaf(g4[0], vq0, fmaf(g4[1], vq1,
                 fmaf(g4[2], vq2, g4[3] * vq3)));
            pp += __shfl_xor(pp, 16); pp += __shfl_xor(pp, 32);
            float s2 = s1 + pp;

            sc = squash_scale(row16_sum(s2 * s2));

            if (hq == 0)
                out[(((size_t)(tile * 16 + brc)) * 32 + k) * 16 + q] = s2 * sc;
        }
    }
}

// ---------------- fallback (round-1 fp32 kernel) if ws too small ----------------
constexpr int WSTRIDE = 260;

__global__ __launch_bounds__(256)
void caps_fused(const float* __restrict__ x,
                const float* __restrict__ W,
                float* __restrict__ out)
{
    __shared__ float wlds[32 * WSTRIDE];

    const int tid  = threadIdx.x;
    const int lane = tid & 63;
    const int wave = tid >> 6;

    const int b    = blockIdx.x;
    const int tq   = b & 15;
    const int kq   = (b >> 4) & 7;
    const int sg   = b >> 7;
    const int k    = (sg & 3) * 8 + kq;
    const int tile = (sg >> 2) * 16 + tq;

    const int brc0 = tile * 8 + wave * 2;
    const int il = lane & 31;
    const int oh = lane >> 5;
    const int ob = oh * 8;

    float res[2][4][8];
#pragma unroll
    for (int t = 0; t < 2; ++t)
#pragma unroll
        for (int r = 0; r < 4; ++r)
#pragma unroll
            for (int q = 0; q < 8; ++q) res[t][r][q] = 0.0f;

    const float* Wk = W + (size_t)k * (128 * 16 * 16);

#pragma unroll
    for (int c = 0; c < 4; ++c) {
        __syncthreads();
#pragma unroll
        for (int j = 0; j < 8; ++j) {
            const int e    = j * 1024 + tid * 4;
            const int irow = e >> 8;
            const int rem  = e & 255;
            *reinterpret_cast<float4*>(&wlds[irow * WSTRIDE + rem]) =
                *reinterpret_cast<const float4*>(&Wk[c * 8192 + e]);
        }
        __syncthreads();

        const int i = c * 32 + il;
        float xv[2][16];
#pragma unroll
        for (int t = 0; t < 2; ++t) {
            const float* xp = x + ((size_t)(brc0 + t) * 128 + i) * 16;
#pragma unroll
            for (int q4 = 0; q4 < 4; ++q4) {
                float4 v4 = *reinterpret_cast<const float4*>(&xp[q4 * 4]);
                xv[t][q4*4+0] = v4.x; xv[t][q4*4+1] = v4.y;
                xv[t][q4*4+2] = v4.z; xv[t][q4*4+3] = v4.w;
            }
        }
        const float* wrow = &wlds[il * WSTRIDE + ob];
#pragma unroll
        for (int d = 0; d < 16; ++d) {
            float4 wa = *reinterpret_cast<const float4*>(&wrow[d * 16]);
            float4 wb = *reinterpret_cast<const float4*>(&wrow[d * 16 + 4]);
            const float w8[8] = {wa.x, wa.y, wa.z, wa.w, wb.x, wb.y, wb.z, wb.w};
#pragma unroll
            for (int t = 0; t < 2; ++t)
#pragma unroll
                for (int q = 0; q < 8; ++q)
                    res[t][c][q] = fmaf(xv[t][d], w8[q], res[t][c][q]);
        }
    }

#pragma unroll
    for (int t = 0; t < 2; ++t) {
        float bb[4] = {1.0f/128.0f, 1.0f/128.0f, 1.0f/128.0f, 1.0f/128.0f};
        float v[8];
#pragma unroll
        for (int iter = 0; iter < 3; ++iter) {
            float s[8];
#pragma unroll
            for (int q = 0; q < 8; ++q) {
                s[q] = bb[0] * res[t][0][q];
#pragma unroll
                for (int r = 1; r < 4; ++r) s[q] = fmaf(bb[r], res[t][r][q], s[q]);
            }
#pragma unroll
            for (int m = 1; m <= 16; m <<= 1)
#pragma unroll
                for (int q = 0; q < 8; ++q) s[q] += __shfl_xor(s[q], m);
            float loc = 0.0f;
#pragma unroll
            for (int q = 0; q < 8; ++q) loc = fmaf(s[q], s[q], loc);
            const float sq = loc + __shfl_xor(loc, 32);
            const float scale = (sq / (1.0f + sq)) / sqrtf(sq + 1e-7f);
#pragma unroll
            for (int q = 0; q < 8; ++q) v[q] = s[q] * scale;
            if (iter < 2) {
#pragma unroll
                for (int r = 0; r < 4; ++r) {
                    float tp = 0.0f;
#pragma unroll
                    for (int q = 0; q < 8; ++q) tp = fmaf(res[t][r][q], v[q], tp);
                    bb[r] += tp + __shfl_xor(tp, 32);
                }
            }
        }
        if (il == 0) {
            float* op = out + ((size_t)(brc0 + t) * 32 + k) * 16 + ob;
            *reinterpret_cast<float4*>(&op[0]) = make_float4(v[0], v[1], v[2], v[3]);
            *reinterpret_cast<float4*>(&op[4]) = make_float4(v[4], v[5], v[6], v[7]);
        }
    }
}

extern "C" void kernel_launch(void* const* d_in, const int* in_sizes, int n_in,
                              void* d_out, int out_size, void* d_ws, size_t ws_size,
                              hipStream_t stream) {
    const float* x  = (const float*)d_in[0];
    const float* W  = (const float*)d_in[1];
    float* out      = (float*)d_out;
    if (ws_size >= WS_NEEDED && d_ws != nullptr) {
        _Float16* ws = (_Float16*)d_ws;
        hipLaunchKernelGGL(prepass, dim3(1536), dim3(256), 0, stream, x, W, ws);
        hipLaunchKernelGGL(caps_g4, dim3(512),  dim3(512), 0, stream, ws, out);
    } else {
        hipLaunchKernelGGL(caps_fused, dim3(4096), dim3(256), 0, stream, x, W, out);
    }
}